// Round 9
// baseline (236.823 us; speedup 1.0000x reference)
//
#include <hip/hip_runtime.h>
#include <hip/hip_bf16.h>

// Grouped GEMM: out[n,g,k] = sum_d x[n*8+g, d] * W[g, k, d]
// Round 9: B never touches LDS.
//  - cvt_w: W f32 -> bf16 FRAGMENT-ORDERED image in d_ws: for each (g,jt,kt)
//    16 KiB = 16 frags (wc,n) x 64 lanes x 16 B. GEMM loads B fragments
//    global->register as coalesced 1 KiB/wave reads (L2-resident: 2.1 MB/XCD).
//  - A: bf16 in LDS via R8's verified micro reg-staging (2 f32x4 loads +
//    1 ds_write_b128/thread/K-tile, 2-tile-deep pipeline, conflict-free
//    (row>>1)&3 involution). LDS = 16 KiB only.
//  - B frags reloaded into the SAME regs right after last MFMA use (in
//    flight across the barrier). No glds, no vmcnt drains; 1 barrier/K-tile.
//  - BM=128 BN=256 BK=32, 8 waves (2Mx4N), acc 4x4=64 AGPR, 2 blocks/CU.

namespace {

constexpr int NG   = 8;
constexpr int DIN  = 1024;
constexpr int DOUT = 1024;
constexpr int BM   = 128;
constexpr int BN   = 256;
constexpr int BK   = 32;
constexpr int NKT  = DIN / BK;            // 32
constexpr int ROWB  = BK * 2;             // 64 B per A-LDS row
constexpr int ATILE = BM * ROWB;          // 8 KiB
constexpr int JTN  = DOUT / BN;           // 4
constexpr int FRAGT = 16 * 1024;          // B frag-tile bytes per (g,jt,kt)
constexpr size_t WSB_BYTES = (size_t)NG * JTN * NKT * FRAGT;  // 16.78 MB

typedef __attribute__((ext_vector_type(8))) short bf16x8;
typedef __attribute__((ext_vector_type(4))) float f32x4;

__device__ __forceinline__ bf16x8 pack_bf16x8v(f32x4 lo, f32x4 hi) {
  union { __hip_bfloat162 h2[4]; bf16x8 v; } p;
  p.h2[0] = __float22bfloat162_rn(make_float2(lo.x, lo.y));
  p.h2[1] = __float22bfloat162_rn(make_float2(lo.z, lo.w));
  p.h2[2] = __float22bfloat162_rn(make_float2(hi.x, hi.y));
  p.h2[3] = __float22bfloat162_rn(make_float2(hi.z, hi.w));
  return p.v;
}

#define FENCE() asm volatile("" ::: "memory")
#define BAR()   do { FENCE(); __builtin_amdgcn_s_barrier(); FENCE(); } while (0)
#define LGKM0() asm volatile("s_waitcnt lgkmcnt(0)" ::: "memory")
#define MFMA_(a, b, c) __builtin_amdgcn_mfma_f32_16x16x32_bf16((a), (b), (c), 0, 0, 0)

// ---------------- cvt_w: W f32 -> bf16 fragment-ordered image ---------------
// one thread per 16-B granule. q -> tile(g,jt,kt) [1024 granules], frag f
// (= wc*4+n), lane l. Granule = B[g, jt*256+(f>>2)*64+(f&3)*16+(l&15),
//                                 kt*32+(l>>4)*8 .. +8) as bf16x8.
__global__ __launch_bounds__(256)
void cvt_w_kernel(const float* __restrict__ W, char* __restrict__ wsB) {
  const int q    = (int)blockIdx.x * 256 + (int)threadIdx.x;
  const int tile = q >> 10;
  const int f    = (q >> 6) & 15;
  const int l    = q & 63;
  const int g    = tile >> 7;
  const int jt   = (tile >> 5) & 3;
  const int kt   = tile & 31;

  const int row = jt * BN + (f >> 2) * 64 + (f & 3) * 16 + (l & 15);
  const int col = kt * BK + (l >> 4) * 8;
  const float* src = W + (size_t)(g * DOUT + row) * DIN + col;
  f32x4 lo = *(const f32x4*)(src);
  f32x4 hi = *(const f32x4*)(src + 4);
  *(bf16x8*)(wsB + (size_t)q * 16) = pack_bf16x8v(lo, hi);
}

// ---------------- K-tile body (static buffer index: rule #20) --------------
// T: tile index; CUR: A LDS buffer. bf[] single-buffered: reloaded for T+1
// right after its last use at T (loads stay in flight across the barrier).
#define KBODY(T, CUR)                                                          \
  {                                                                            \
    const int t_ = (T);                                                        \
    char* const cA = smA + (CUR) * ATILE;                                      \
    char* const nA = smA + (1 - (CUR)) * ATILE;                                \
    const bool st1 = (t_ + 1) < NKT;                                           \
    const bool st2 = (t_ + 2) < NKT;                                           \
    if (st2) {  /* A(t+2) global loads: ~2 K-tiles in flight */                \
      const float* An = aSrc + (size_t)(t_ + 2) * BK;                          \
      aS[CUR][0] = *(const f32x4*)(An);                                        \
      aS[CUR][1] = *(const f32x4*)(An + 4);                                    \
    }                                                                          \
    __builtin_amdgcn_s_setprio(1);                                             \
    _Pragma("unroll")                                                          \
    for (int m = 0; m < 4; ++m) {                                              \
      bf16x8 am = *(const bf16x8*)(cA + aoff + m * 1024);                      \
      _Pragma("unroll")                                                        \
      for (int n = 0; n < 4; ++n)                                              \
        acc[m][n] = MFMA_(am, bf[n], acc[m][n]);                               \
    }                                                                          \
    __builtin_amdgcn_s_setprio(0);                                             \
    if (st1) {                                                                 \
      if (WSB) {  /* reload B frags for t+1 (same regs, post-last-use) */      \
        const char* Bn = BgF + (size_t)(t_ + 1) * FRAGT;                       \
        _Pragma("unroll")                                                      \
        for (int n = 0; n < 4; ++n)                                            \
          bf[n] = *(const bf16x8*)(Bn + n * 1024);                             \
      } else {                                                                 \
        _Pragma("unroll")                                                      \
        for (int n = 0; n < 4; ++n) {                                          \
          const float* bp = bSrcF + (size_t)n * 16 * DIN + (t_ + 1) * BK;      \
          bf[n] = pack_bf16x8v(*(const f32x4*)(bp), *(const f32x4*)(bp + 4));  \
        }                                                                      \
      }                                                                        \
      /* cvt+write A(t+1) from aS loaded at t-1 (counted vmcnt) */             \
      *(bf16x8*)(nA + tid * 16) = pack_bf16x8v(aS[1 - (CUR)][0],               \
                                               aS[1 - (CUR)][1]);              \
      LGKM0();                                                                 \
      BAR();                                                                   \
    }                                                                          \
  }

// ---------------- gemm ------------------------------------------------------
template <bool WSB>
__global__ __launch_bounds__(512, 4)
void gemm_k(const float* __restrict__ X, const float* __restrict__ W,
            const char* __restrict__ wsB, float* __restrict__ O) {
  __shared__ __align__(16) char smA[2 * ATILE];   // 16 KiB bf16, swizzled

  // ---- block mapping: group == XCD (2048 blocks, 256/XCD), bijective
  const int bid = (int)blockIdx.x;
  const int swz = (bid & 7) * 256 + (bid >> 3);
  const int jt = swz & 3;                 // col panel [0,4) fastest (A reuse)
  const int it = (swz >> 2) & 63;         // row tile  [0,64)
  const int g  = swz >> 8;                // group     [0,8)  == XCD

  const int n0 = it * BM;
  const int c0 = jt * BN;

  const int tid  = (int)threadIdx.x;
  const int lane = tid & 63;
  const int wid  = tid >> 6;              // 8 waves: 2(M) x 4(N)
  const int wr   = wid >> 2;
  const int wc   = wid & 3;
  const int fr   = lane & 15;
  const int fq   = lane >> 4;

  // ---- A staging (R8-verified): row tid>>2, dest granule tid&3 (linear
  // tid*16); SOURCE chunk = (tid&3) ^ ((row>>1)&3) = (tid&3)^((tid>>3)&3).
  const int aRow = tid >> 2;
  const int aChk = (tid & 3) ^ ((tid >> 3) & 3);
  const float* aSrc = X + ((size_t)(n0 + aRow) * NG + g) * DIN + aChk * 8;

  // ---- B fragment stream: image (WSB) or raw W (fallback, slow-correct)
  const char* BgF = wsB + (size_t)((g * JTN + jt) * NKT) * FRAGT
                        + (wc * 4) * 1024 + lane * 16;
  const float* bSrcF = W + (size_t)(g * DOUT + c0 + wc * 64 + fr) * DIN
                         + fq * 8;

  // ---- A fragment LDS addressing (conflict-free involution, R8-measured)
  const int aoff = (wr * 64 + fr) * ROWB + ((fq ^ ((fr >> 1) & 3)) << 4);

  f32x4 aS[2][2];
  bf16x8 bf[4];
  f32x4 acc[4][4];
#pragma unroll
  for (int m = 0; m < 4; ++m)
#pragma unroll
    for (int n = 0; n < 4; ++n) acc[m][n] = (f32x4){0.f, 0.f, 0.f, 0.f};

  // ---- prologue: A(0)->aS[0], B(0) frags, A(1)->aS[1]; write A(0); publish
  aS[0][0] = *(const f32x4*)(aSrc);
  aS[0][1] = *(const f32x4*)(aSrc + 4);
  if (WSB) {
#pragma unroll
    for (int n = 0; n < 4; ++n)
      bf[n] = *(const bf16x8*)(BgF + n * 1024);
  } else {
#pragma unroll
    for (int n = 0; n < 4; ++n) {
      const float* bp = bSrcF + (size_t)n * 16 * DIN;
      bf[n] = pack_bf16x8v(*(const f32x4*)(bp), *(const f32x4*)(bp + 4));
    }
  }
  aS[1][0] = *(const f32x4*)(aSrc + BK);
  aS[1][1] = *(const f32x4*)(aSrc + BK + 4);
  *(bf16x8*)(smA + tid * 16) = pack_bf16x8v(aS[0][0], aS[0][1]);
  LGKM0();
  BAR();

  for (int tt = 0; tt < NKT; tt += 2) {
    KBODY(tt, 0);
    KBODY(tt + 1, 1);
  }

  // ---- epilogue: C/D layout col = lane&15, row = (lane>>4)*4 + reg (m89)
#pragma unroll
  for (int m = 0; m < 4; ++m) {
#pragma unroll
    for (int r = 0; r < 4; ++r) {
      const int row = wr * 64 + m * 16 + fq * 4 + r;
      float* orow = O + ((size_t)(n0 + row) * NG + g) * DOUT + c0 + wc * 64;
#pragma unroll
      for (int n = 0; n < 4; ++n) {
        orow[n * 16 + fr] = acc[m][n][r];
      }
    }
  }
}

} // namespace

extern "C" void kernel_launch(void* const* d_in, const int* in_sizes, int n_in,
                              void* d_out, int out_size, void* d_ws, size_t ws_size,
                              hipStream_t stream) {
  (void)n_in; (void)out_size;
  const float* X = (const float*)d_in[0];
  const float* W = (const float*)d_in[1];
  float* O = (float*)d_out;

  const int tokens_total = in_sizes[0] / DIN;            // 65536
  const int ntok_per_g   = tokens_total / NG;            // 8192
  const int grid = NG * (ntok_per_g / BM) * (DOUT / BN); // 2048

  if (ws_size >= WSB_BYTES) {
    const int cvt_grid = (int)(WSB_BYTES / 16 / 256);    // 4096
    cvt_w_kernel<<<dim3(cvt_grid), dim3(256), 0, stream>>>(W, (char*)d_ws);
    gemm_k<true><<<dim3(grid), dim3(512), 0, stream>>>(
        X, W, (const char*)d_ws, O);
  } else {
    gemm_k<false><<<dim3(grid), dim3(512), 0, stream>>>(
        X, W, nullptr, O);
  }
}